// Round 6
// baseline (241.035 us; speedup 1.0000x reference)
//
#include <hip/hip_runtime.h>
#include <cstdint>

#define IND 128
#define HID 64
#define NEG_SLOPE 0.2f
#define LSTRIDE 132   // 128 + 4: 16B-aligned rows, (stride*4) % 32 banks == 16
#define BSHIFT 4      // bucket = 16 consecutive dst nodes (n < 65536 required)
#define BS (1 << BSHIFT)

// ---------------------------------------------------------------------------
// K1: h = x @ W.T ; a_src = h @ att_src ; a_dst = h @ att_dst
// Tiled GEMM: block = 64 nodes x 64 hid x K=128, microtile 4x4.
// ---------------------------------------------------------------------------
__global__ __launch_bounds__(256) void k_proj(
    const float* __restrict__ x, const float* __restrict__ W,
    const float* __restrict__ att_s, const float* __restrict__ att_d,
    float* __restrict__ h, float* __restrict__ a_src, float* __restrict__ a_dst,
    int n)
{
  __shared__ float xs[64 * LSTRIDE];
  __shared__ float wt[64 * LSTRIDE];
  __shared__ float sa_l[64], sd_l[64];

  const int tid = threadIdx.x;
  const int nodeBase = blockIdx.x * 64;

  if (tid < 64) { sa_l[tid] = 0.f; sd_l[tid] = 0.f; }

#pragma unroll
  for (int it = 0; it < 8; ++it) {
    int fi = (it * 256 + tid) * 4;
    int hid = fi >> 7, k = fi & 127;
    float4 v = *(const float4*)(W + fi);
    *(float4*)&wt[hid * LSTRIDE + k] = v;
  }
#pragma unroll
  for (int it = 0; it < 8; ++it) {
    int fi = (it * 256 + tid) * 4;
    int nl = fi >> 7, k = fi & 127;
    int node = nodeBase + nl; if (node >= n) node = n - 1;
    float4 v = *(const float4*)(x + (size_t)node * IND + k);
    *(float4*)&xs[nl * LSTRIDE + k] = v;
  }
  __syncthreads();

  const int ng = tid & 15;
  const int hg = tid >> 4;
  const float* xrow0 = &xs[(4 * ng) * LSTRIDE];
  const float* wrow0 = &wt[(4 * hg) * LSTRIDE];

  float acc[4][4];
#pragma unroll
  for (int j = 0; j < 4; ++j)
#pragma unroll
    for (int i = 0; i < 4; ++i) acc[j][i] = 0.f;

  for (int k = 0; k < IND; k += 4) {
    float4 a[4], b[4];
#pragma unroll
    for (int j = 0; j < 4; ++j) a[j] = *(const float4*)(xrow0 + j * LSTRIDE + k);
#pragma unroll
    for (int i = 0; i < 4; ++i) b[i] = *(const float4*)(wrow0 + i * LSTRIDE + k);
#pragma unroll
    for (int j = 0; j < 4; ++j)
#pragma unroll
      for (int i = 0; i < 4; ++i) {
        acc[j][i] = fmaf(a[j].x, b[i].x, acc[j][i]);
        acc[j][i] = fmaf(a[j].y, b[i].y, acc[j][i]);
        acc[j][i] = fmaf(a[j].z, b[i].z, acc[j][i]);
        acc[j][i] = fmaf(a[j].w, b[i].w, acc[j][i]);
      }
  }

#pragma unroll
  for (int j = 0; j < 4; ++j) {
    int node = nodeBase + 4 * ng + j;
    if (node < n)
      *(float4*)(h + (size_t)node * HID + 4 * hg) =
          make_float4(acc[j][0], acc[j][1], acc[j][2], acc[j][3]);
  }

  float4 as4 = *(const float4*)(att_s + 4 * hg);
  float4 ad4 = *(const float4*)(att_d + 4 * hg);
#pragma unroll
  for (int j = 0; j < 4; ++j) {
    float ps = acc[j][0]*as4.x + acc[j][1]*as4.y + acc[j][2]*as4.z + acc[j][3]*as4.w;
    float pd = acc[j][0]*ad4.x + acc[j][1]*ad4.y + acc[j][2]*ad4.z + acc[j][3]*ad4.w;
    ps += __shfl_xor(ps, 16, 64); ps += __shfl_xor(ps, 32, 64);
    pd += __shfl_xor(pd, 16, 64); pd += __shfl_xor(pd, 32, 64);
    if ((tid & 63) < 16) {
      atomicAdd(&sa_l[4 * ng + j], ps);
      atomicAdd(&sd_l[4 * ng + j], pd);
    }
  }
  __syncthreads();
  if (tid < 64) {
    int node = nodeBase + tid;
    if (node < n) { a_src[node] = sa_l[tid]; a_dst[node] = sd_l[tid]; }
  }
}

// ---------------------------------------------------------------------------
// K2: histogram of real-edge in-degrees (deg[] pre-zeroed).
// ---------------------------------------------------------------------------
__global__ __launch_bounds__(256) void k_hist(
    const int* __restrict__ ei, int* __restrict__ deg, int E)
{
  long long idx = (long long)blockIdx.x * 256 + threadIdx.x;
  if (idx >= E) return;
  atomicAdd(deg + ei[E + idx], 1);
}

// ---------------------------------------------------------------------------
// K3a/b/c: multi-block exclusive scan of (deg[i]+1) -> row_start.
// ---------------------------------------------------------------------------
__global__ __launch_bounds__(256) void k_scan_a(
    const int* __restrict__ deg, int* __restrict__ blockSums, int n)
{
  __shared__ int red[4];
  int i = blockIdx.x * 256 + threadIdx.x;
  int v = (i < n) ? deg[i] + 1 : 0;
#pragma unroll
  for (int o = 32; o; o >>= 1) v += __shfl_xor(v, o, 64);
  if ((threadIdx.x & 63) == 0) red[threadIdx.x >> 6] = v;
  __syncthreads();
  if (threadIdx.x == 0)
    blockSums[blockIdx.x] = red[0] + red[1] + red[2] + red[3];
}

__global__ __launch_bounds__(1024) void k_scan_b(
    int* __restrict__ blockSums, int nb)
{
  __shared__ int sums[1024];
  const int tid = threadIdx.x;
  int v = (tid < nb) ? blockSums[tid] : 0;
  sums[tid] = v;
  __syncthreads();
  for (int off = 1; off < 1024; off <<= 1) {
    int t = (tid >= off) ? sums[tid - off] : 0;
    __syncthreads();
    sums[tid] += t;
    __syncthreads();
  }
  if (tid < nb) blockSums[tid] = sums[tid] - v;
}

__global__ __launch_bounds__(256) void k_scan_c(
    const int* __restrict__ deg, const int* __restrict__ blockSums,
    int* __restrict__ row_start, int n)
{
  __shared__ int sums[256];
  const int tid = threadIdx.x;
  int i = blockIdx.x * 256 + tid;
  int v = (i < n) ? deg[i] + 1 : 0;
  sums[tid] = v;
  __syncthreads();
  for (int off = 1; off < 256; off <<= 1) {
    int t = (tid >= off) ? sums[tid - off] : 0;
    __syncthreads();
    sums[tid] += t;
    __syncthreads();
  }
  int ex = sums[tid] - v + blockSums[blockIdx.x];
  if (i < n) row_start[i] = ex;
}

// ---------------------------------------------------------------------------
// K4a: bin pass. Edge -> its dst-bucket's contiguous tmp window (the final
// CSR region of those 16 nodes), position via line-padded bucket cursor.
// Payload packed 4B: (dst<<16)|src  (valid while n < 65536).
// Dense-in-time small-window writes -> lines fill, minimal amplification.
// ---------------------------------------------------------------------------
__global__ __launch_bounds__(256) void k_bin(
    const int* __restrict__ ei, const int* __restrict__ row_start,
    int* __restrict__ bcur, unsigned* __restrict__ tmp, int E, int n)
{
  long long idx = (long long)blockIdx.x * 256 + threadIdx.x;
  long long E2 = (long long)E + n;
  if (idx >= E2) return;
  int s, d;
  if (idx < E) { s = ei[idx]; d = ei[E + idx]; }
  else         { s = d = (int)(idx - E); }
  int b    = d >> BSHIFT;
  int base = row_start[b << BSHIFT];
  int pos  = base + atomicAdd(bcur + (b << 4), 1);   // 64B-padded cursor
  tmp[pos] = ((unsigned)d << 16) | (unsigned)s;
}

// ---------------------------------------------------------------------------
// K4b: within-bucket scatter. Block per bucket: cursors + a_dst slice in LDS
// (no global atomics), contiguous tmp read, computes w = exp(leaky_relu(.)),
// 8B stores into the bucket's ~1KB final CSR window.
// ---------------------------------------------------------------------------
__global__ __launch_bounds__(256) void k_scatter2(
    const unsigned* __restrict__ tmp, const int* __restrict__ row_start,
    const float* __restrict__ a_src, const float* __restrict__ a_dst,
    float2* __restrict__ csr, int E2total, int n)
{
  __shared__ int   cur[BS];
  __shared__ float adl[BS];
  const int tid = threadIdx.x;
  const int n0  = blockIdx.x << BSHIFT;

  if (tid < BS) {
    int node = n0 + tid;
    cur[tid] = (node < n) ? row_start[node] : 0;
    adl[tid] = (node < n) ? a_dst[node] : 0.f;
  }
  __syncthreads();

  const int base = row_start[n0];
  const int next = (n0 + BS < n) ? row_start[n0 + BS] : E2total;
  const int cnt  = next - base;

  for (int t = tid; t < cnt; t += 256) {
    unsigned p = tmp[base + t];
    int s  = (int)(p & 0xFFFFu);
    int dl = (int)(p >> 16) - n0;
    float v = a_src[s] + adl[dl];
    v = (v >= 0.f) ? v : NEG_SLOPE * v;
    float w = expf(v);
    int pos = atomicAdd(&cur[dl], 1);
    csr[pos] = make_float2(__int_as_float(s), w);
  }
}

// ---------------------------------------------------------------------------
// K5: per-node softmax-normalize + gather-aggregate + relu + W_lin + sigmoid.
// ---------------------------------------------------------------------------
__global__ __launch_bounds__(256) void k_gather_final(
    const int* __restrict__ row_start, const int* __restrict__ deg,
    const float2* __restrict__ csr, const float* __restrict__ h,
    const float* __restrict__ bias, const float* __restrict__ W_lin,
    const float* __restrict__ b_lin, float* __restrict__ y, int n)
{
  const int lane = threadIdx.x & 63;
  const int wid  = threadIdx.x >> 6;
  const int node = blockIdx.x * 4 + wid;
  if (node >= n) return;

  const int rs = row_start[node];
  const int dg = deg[node] + 1;

  float part = 0.f;
  for (int b = 0; b < dg; b += 64) {
    int i = b + lane;
    if (i < dg) part += csr[rs + i].y;
  }
  float ssum = part;
#pragma unroll
  for (int o = 32; o; o >>= 1) ssum += __shfl_xor(ssum, o, 64);
  const float inv = 1.f / ssum;

  float acc = 0.f;
  for (int b = 0; b < dg; b += 64) {
    int i = b + lane;
    float2 pk = (i < dg) ? csr[rs + i] : make_float2(0.f, 0.f);
    int   srcl = __float_as_int(pk.x);
    float wl   = pk.y * inv;
    const int cnt = (dg - b < 64) ? dg - b : 64;

    int j = 0;
    for (; j + 4 <= cnt; j += 4) {
      int   s0 = __shfl(srcl, j,     64), s1 = __shfl(srcl, j + 1, 64);
      int   s2 = __shfl(srcl, j + 2, 64), s3 = __shfl(srcl, j + 3, 64);
      float w0 = __shfl(wl,   j,     64), w1 = __shfl(wl,   j + 1, 64);
      float w2 = __shfl(wl,   j + 2, 64), w3 = __shfl(wl,   j + 3, 64);
      float h0 = h[(size_t)s0 * HID + lane];
      float h1 = h[(size_t)s1 * HID + lane];
      float h2 = h[(size_t)s2 * HID + lane];
      float h3 = h[(size_t)s3 * HID + lane];
      acc = fmaf(w0, h0, acc);
      acc = fmaf(w1, h1, acc);
      acc = fmaf(w2, h2, acc);
      acc = fmaf(w3, h3, acc);
    }
    for (; j < cnt; ++j) {
      int   sj = __shfl(srcl, j, 64);
      float wj = __shfl(wl,   j, 64);
      acc = fmaf(wj, h[(size_t)sj * HID + lane], acc);
    }
  }

  float v = fmaxf(acc + bias[lane], 0.f);
  float z = v * W_lin[lane];
#pragma unroll
  for (int o = 32; o; o >>= 1) z += __shfl_xor(z, o, 64);
  if (lane == 0) {
    z += b_lin[0];
    y[node] = 1.f / (1.f + expf(-z));
  }
}

// ---------------------------------------------------------------------------

extern "C" void kernel_launch(void* const* d_in, const int* in_sizes, int n_in,
                              void* d_out, int out_size, void* d_ws, size_t ws_size,
                              hipStream_t stream)
{
  const float* x     = (const float*)d_in[0];
  const int*   ei    = (const int*)d_in[1];
  const float* W     = (const float*)d_in[2];
  const float* att_s = (const float*)d_in[3];
  const float* att_d = (const float*)d_in[4];
  const float* bias  = (const float*)d_in[5];
  const float* W_lin = (const float*)d_in[6];
  const float* b_lin = (const float*)d_in[7];
  float* y = (float*)d_out;

  const int n = in_sizes[0] / IND;
  const int E = in_sizes[1] / 2;
  const long long E2 = (long long)E + n;
  const int nb    = (n + 255) / 256;          // scan blocks
  const int nbuck = (n + BS - 1) / BS;        // dst buckets

  // Workspace carve-up
  char* ws = (char*)d_ws;
  float*    h      = (float*)ws;    ws += (size_t)n * HID * sizeof(float);
  float*    a_src  = (float*)ws;    ws += (size_t)n * sizeof(float);
  float*    a_dst  = (float*)ws;    ws += (size_t)n * sizeof(float);
  int*      deg    = (int*)ws;      ws += (size_t)n * sizeof(int);
  int*      bcur   = (int*)ws;      ws += (size_t)nbuck * 16 * sizeof(int); // 64B-padded
  int*      row_st = (int*)ws;      ws += (size_t)n * sizeof(int);
  int*      bsums  = (int*)ws;      ws += (size_t)1024 * sizeof(int);
  unsigned* tmp    = (unsigned*)ws; ws += (size_t)E2 * sizeof(unsigned);
  float2*   csr    = (float2*)ws;   ws += (size_t)E2 * sizeof(float2);

  // deg + bcur are adjacent -> single zeroing memset. Re-init every call
  // (ws re-poisoned to 0xAA by the harness).
  hipMemsetAsync(deg, 0, (size_t)(n + nbuck * 16) * sizeof(int), stream);

  k_hist<<<(E + 255) / 256, 256, 0, stream>>>(ei, deg, E);
  k_scan_a<<<nb, 256, 0, stream>>>(deg, bsums, n);
  k_scan_b<<<1, 1024, 0, stream>>>(bsums, nb);
  k_scan_c<<<nb, 256, 0, stream>>>(deg, bsums, row_st, n);

  k_proj<<<(n + 63) / 64, 256, 0, stream>>>(x, W, att_s, att_d, h, a_src, a_dst, n);

  k_bin<<<(int)((E2 + 255) / 256), 256, 0, stream>>>(ei, row_st, bcur, tmp, E, n);
  k_scatter2<<<nbuck, 256, 0, stream>>>(tmp, row_st, a_src, a_dst, csr, (int)E2, n);

  k_gather_final<<<(n + 3) / 4, 256, 0, stream>>>(
      row_st, deg, csr, h, bias, W_lin, b_lin, y, n);
}

// Round 7
// 184.268 us; speedup vs baseline: 1.3081x; 1.3081x over previous
//
#include <hip/hip_runtime.h>
#include <cstdint>

#define IND 128
#define HID 64
#define NEG_SLOPE 0.2f
#define LSTRIDE 132   // 128 + 4: 16B-aligned rows for LDS GEMM tiles
#define EPB 4096      // edges per sort block
#define CBSHIFT 8     // coarse bucket = 256 consecutive dst nodes

// ---------------------------------------------------------------------------
// K1: h = x @ W.T ; a_src = h @ att_src ; a_dst = h @ att_dst
// Tiled GEMM: block = 64 nodes x 64 hid x K=128, microtile 4x4.
// ---------------------------------------------------------------------------
__global__ __launch_bounds__(256) void k_proj(
    const float* __restrict__ x, const float* __restrict__ W,
    const float* __restrict__ att_s, const float* __restrict__ att_d,
    float* __restrict__ h, float* __restrict__ a_src, float* __restrict__ a_dst,
    int n)
{
  __shared__ float xs[64 * LSTRIDE];
  __shared__ float wt[64 * LSTRIDE];
  __shared__ float sa_l[64], sd_l[64];

  const int tid = threadIdx.x;
  const int nodeBase = blockIdx.x * 64;

  if (tid < 64) { sa_l[tid] = 0.f; sd_l[tid] = 0.f; }

#pragma unroll
  for (int it = 0; it < 8; ++it) {
    int fi = (it * 256 + tid) * 4;
    int hid = fi >> 7, k = fi & 127;
    float4 v = *(const float4*)(W + fi);
    *(float4*)&wt[hid * LSTRIDE + k] = v;
  }
#pragma unroll
  for (int it = 0; it < 8; ++it) {
    int fi = (it * 256 + tid) * 4;
    int nl = fi >> 7, k = fi & 127;
    int node = nodeBase + nl; if (node >= n) node = n - 1;
    float4 v = *(const float4*)(x + (size_t)node * IND + k);
    *(float4*)&xs[nl * LSTRIDE + k] = v;
  }
  __syncthreads();

  const int ng = tid & 15;
  const int hg = tid >> 4;
  const float* xrow0 = &xs[(4 * ng) * LSTRIDE];
  const float* wrow0 = &wt[(4 * hg) * LSTRIDE];

  float acc[4][4];
#pragma unroll
  for (int j = 0; j < 4; ++j)
#pragma unroll
    for (int i = 0; i < 4; ++i) acc[j][i] = 0.f;

  for (int k = 0; k < IND; k += 4) {
    float4 a[4], b[4];
#pragma unroll
    for (int j = 0; j < 4; ++j) a[j] = *(const float4*)(xrow0 + j * LSTRIDE + k);
#pragma unroll
    for (int i = 0; i < 4; ++i) b[i] = *(const float4*)(wrow0 + i * LSTRIDE + k);
#pragma unroll
    for (int j = 0; j < 4; ++j)
#pragma unroll
      for (int i = 0; i < 4; ++i) {
        acc[j][i] = fmaf(a[j].x, b[i].x, acc[j][i]);
        acc[j][i] = fmaf(a[j].y, b[i].y, acc[j][i]);
        acc[j][i] = fmaf(a[j].z, b[i].z, acc[j][i]);
        acc[j][i] = fmaf(a[j].w, b[i].w, acc[j][i]);
      }
  }

#pragma unroll
  for (int j = 0; j < 4; ++j) {
    int node = nodeBase + 4 * ng + j;
    if (node < n)
      *(float4*)(h + (size_t)node * HID + 4 * hg) =
          make_float4(acc[j][0], acc[j][1], acc[j][2], acc[j][3]);
  }

  float4 as4 = *(const float4*)(att_s + 4 * hg);
  float4 ad4 = *(const float4*)(att_d + 4 * hg);
#pragma unroll
  for (int j = 0; j < 4; ++j) {
    float ps = acc[j][0]*as4.x + acc[j][1]*as4.y + acc[j][2]*as4.z + acc[j][3]*as4.w;
    float pd = acc[j][0]*ad4.x + acc[j][1]*ad4.y + acc[j][2]*ad4.z + acc[j][3]*ad4.w;
    ps += __shfl_xor(ps, 16, 64); ps += __shfl_xor(ps, 32, 64);
    pd += __shfl_xor(pd, 16, 64); pd += __shfl_xor(pd, 32, 64);
    if ((tid & 63) < 16) {
      atomicAdd(&sa_l[4 * ng + j], ps);
      atomicAdd(&sd_l[4 * ng + j], pd);
    }
  }
  __syncthreads();
  if (tid < 64) {
    int node = nodeBase + tid;
    if (node < n) { a_src[node] = sa_l[tid]; a_dst[node] = sd_l[tid]; }
  }
}

// ---------------------------------------------------------------------------
// K2: per-(sort block, coarse bucket) histogram. cnt is bucket-major:
// cnt[bucket * nblk + block]. Edges [E, E+n) are self-loops.
// ---------------------------------------------------------------------------
__global__ __launch_bounds__(256) void k_cnt(
    const int* __restrict__ ei, int* __restrict__ cnt,
    int E, long long E2, int nblk, int nbuck)
{
  __shared__ int hist[256];
  const int tid = threadIdx.x;
  hist[tid] = 0;
  __syncthreads();

  const long long i0 = (long long)blockIdx.x * EPB;
  const int cntE = (int)((E2 - i0 < EPB) ? (E2 - i0) : EPB);
  for (int j = tid; j < cntE; j += 256) {
    long long idx = i0 + j;
    int d = (idx < E) ? ei[E + idx] : (int)(idx - E);
    atomicAdd(&hist[d >> CBSHIFT], 1);
  }
  __syncthreads();
  if (tid < nbuck) cnt[tid * nblk + blockIdx.x] = hist[tid];
}

// ---------------------------------------------------------------------------
// K3a/b/c: multi-block exclusive scan of cnt[0..cntN) -> cntS.
// ---------------------------------------------------------------------------
__global__ __launch_bounds__(256) void k_scan_a(
    const int* __restrict__ vals, int* __restrict__ blockSums, int cntN)
{
  __shared__ int red[4];
  int i = blockIdx.x * 256 + threadIdx.x;
  int v = (i < cntN) ? vals[i] : 0;
#pragma unroll
  for (int o = 32; o; o >>= 1) v += __shfl_xor(v, o, 64);
  if ((threadIdx.x & 63) == 0) red[threadIdx.x >> 6] = v;
  __syncthreads();
  if (threadIdx.x == 0)
    blockSums[blockIdx.x] = red[0] + red[1] + red[2] + red[3];
}

__global__ __launch_bounds__(1024) void k_scan_b(
    int* __restrict__ blockSums, int nb)
{
  __shared__ int sums[1024];
  const int tid = threadIdx.x;
  int v = (tid < nb) ? blockSums[tid] : 0;
  sums[tid] = v;
  __syncthreads();
  for (int off = 1; off < 1024; off <<= 1) {
    int t = (tid >= off) ? sums[tid - off] : 0;
    __syncthreads();
    sums[tid] += t;
    __syncthreads();
  }
  if (tid < nb) blockSums[tid] = sums[tid] - v;
}

__global__ __launch_bounds__(256) void k_scan_c(
    const int* __restrict__ vals, const int* __restrict__ blockSums,
    int* __restrict__ out, int cntN)
{
  __shared__ int sums[256];
  const int tid = threadIdx.x;
  int i = blockIdx.x * 256 + tid;
  int v = (i < cntN) ? vals[i] : 0;
  sums[tid] = v;
  __syncthreads();
  for (int off = 1; off < 256; off <<= 1) {
    int t = (tid >= off) ? sums[tid - off] : 0;
    __syncthreads();
    sums[tid] += t;
    __syncthreads();
  }
  if (i < cntN) out[i] = sums[tid] - v + blockSums[blockIdx.x];
}

// ---------------------------------------------------------------------------
// K4: block-level counting sort of this block's EPB edges by coarse bucket,
// then LINEAR write-out: consecutive sorted indices -> consecutive global
// addresses within each bucket run. All bytes of a line written by this one
// block -> lines fill (the round-6 lesson). Packed 4B: (dst<<16)|src.
// ---------------------------------------------------------------------------
__global__ __launch_bounds__(256) void k_sortout(
    const int* __restrict__ ei, const int* __restrict__ cntS,
    unsigned* __restrict__ tmp, int E, long long E2, int nblk, int nbuck)
{
  __shared__ int hist[256];     // counts, then lstart (exclusive)
  __shared__ int sums[256];
  __shared__ int cur[256];
  __shared__ int gbase[256];
  __shared__ unsigned sorted[EPB];

  const int tid = threadIdx.x;
  hist[tid] = 0;
  __syncthreads();

  const long long i0 = (long long)blockIdx.x * EPB;

  unsigned pk[EPB / 256];
#pragma unroll
  for (int j = 0; j < EPB / 256; ++j) {
    long long idx = i0 + j * 256 + tid;
    unsigned v = 0xFFFFFFFFu;
    if (idx < E2) {
      int s, d;
      if (idx < E) { s = ei[idx]; d = ei[E + idx]; }
      else         { s = d = (int)(idx - E); }
      v = ((unsigned)d << 16) | (unsigned)s;
      atomicAdd(&hist[d >> CBSHIFT], 1);
    }
    pk[j] = v;
  }
  __syncthreads();

  // block scan of hist -> exclusive lstart
  sums[tid] = hist[tid];
  __syncthreads();
  for (int off = 1; off < 256; off <<= 1) {
    int t = (tid >= off) ? sums[tid - off] : 0;
    __syncthreads();
    sums[tid] += t;
    __syncthreads();
  }
  const int lstart_t = sums[tid] - hist[tid];
  cur[tid] = lstart_t;
  gbase[tid] = (tid < nbuck) ? cntS[tid * nblk + blockIdx.x] : 0;
  __syncthreads();
  hist[tid] = lstart_t;          // hist now holds lstart
  __syncthreads();

  // scatter into LDS sorted order
#pragma unroll
  for (int j = 0; j < EPB / 256; ++j) {
    unsigned v = pk[j];
    if (v != 0xFFFFFFFFu) {
      int b = v >> (16 + CBSHIFT);          // dst >> CBSHIFT
      int lpos = atomicAdd(&cur[b], 1);
      sorted[lpos] = v;
    }
  }
  __syncthreads();

  // linear write-out
  const int cntE = (int)((E2 - i0 < EPB) ? (E2 - i0) : EPB);
  for (int i = tid; i < cntE; i += 256) {
    unsigned v = sorted[i];
    int b = v >> (16 + CBSHIFT);
    tmp[gbase[b] + (i - hist[b])] = v;
  }
}

// ---------------------------------------------------------------------------
// K5: per-coarse-bucket exact CSR + edge score. One block owns the bucket's
// contiguous CSR region (~35KB): LDS deg -> scan -> row_start (n+1 array),
// LDS cursors -> csr {src, w=exp(leaky_relu(a_src+a_dst))}.
// ---------------------------------------------------------------------------
__global__ __launch_bounds__(256) void k_csr(
    const unsigned* __restrict__ tmp, const int* __restrict__ cntS,
    const float* __restrict__ a_src, const float* __restrict__ a_dst,
    int* __restrict__ row_start, float2* __restrict__ csr,
    int E2total, int n, int nblk, int nbuck)
{
  __shared__ int degl[256], sums[256], cur[256];
  __shared__ float adl[256];

  const int tid = threadIdx.x;
  const int b   = blockIdx.x;
  const int n0  = b << CBSHIFT;
  const int base = cntS[b * nblk];
  const int next = (b + 1 < nbuck) ? cntS[(b + 1) * nblk] : E2total;

  degl[tid] = 0;
  const int node = n0 + tid;
  adl[tid] = (node < n) ? a_dst[node] : 0.f;
  __syncthreads();

  for (int i = base + tid; i < next; i += 256)
    atomicAdd(&degl[(tmp[i] >> 16) - n0], 1);
  __syncthreads();

  sums[tid] = degl[tid];
  __syncthreads();
  for (int off = 1; off < 256; off <<= 1) {
    int t = (tid >= off) ? sums[tid - off] : 0;
    __syncthreads();
    sums[tid] += t;
    __syncthreads();
  }
  const int rs = base + sums[tid] - degl[tid];
  cur[tid] = rs;
  if (node < n) row_start[node] = rs;
  if (b == nbuck - 1 && tid == 0) row_start[n] = E2total;
  __syncthreads();

  for (int i = base + tid; i < next; i += 256) {
    unsigned v = tmp[i];
    int s  = (int)(v & 0xFFFFu);
    int dl = (int)(v >> 16) - n0;
    float sc = a_src[s] + adl[dl];
    sc = (sc >= 0.f) ? sc : NEG_SLOPE * sc;
    int pos = atomicAdd(&cur[dl], 1);
    csr[pos] = make_float2(__int_as_float(s), expf(sc));
  }
}

// ---------------------------------------------------------------------------
// K6: per-node softmax-normalize + gather-aggregate + relu + W_lin + sigmoid.
// One wave per node; lane = hidden dim; shfl broadcast; 4x-unrolled gathers.
// ---------------------------------------------------------------------------
__global__ __launch_bounds__(256) void k_gather_final(
    const int* __restrict__ row_start, const float2* __restrict__ csr,
    const float* __restrict__ h, const float* __restrict__ bias,
    const float* __restrict__ W_lin, const float* __restrict__ b_lin,
    float* __restrict__ y, int n)
{
  const int lane = threadIdx.x & 63;
  const int wid  = threadIdx.x >> 6;
  const int node = blockIdx.x * 4 + wid;
  if (node >= n) return;

  const int rs = row_start[node];
  const int dg = row_start[node + 1] - rs;

  float part = 0.f;
  for (int b = 0; b < dg; b += 64) {
    int i = b + lane;
    if (i < dg) part += csr[rs + i].y;
  }
  float ssum = part;
#pragma unroll
  for (int o = 32; o; o >>= 1) ssum += __shfl_xor(ssum, o, 64);
  const float inv = 1.f / ssum;

  float acc = 0.f;
  for (int b = 0; b < dg; b += 64) {
    int i = b + lane;
    float2 pk = (i < dg) ? csr[rs + i] : make_float2(0.f, 0.f);
    int   srcl = __float_as_int(pk.x);
    float wl   = pk.y * inv;
    const int cnt = (dg - b < 64) ? dg - b : 64;

    int j = 0;
    for (; j + 4 <= cnt; j += 4) {
      int   s0 = __shfl(srcl, j,     64), s1 = __shfl(srcl, j + 1, 64);
      int   s2 = __shfl(srcl, j + 2, 64), s3 = __shfl(srcl, j + 3, 64);
      float w0 = __shfl(wl,   j,     64), w1 = __shfl(wl,   j + 1, 64);
      float w2 = __shfl(wl,   j + 2, 64), w3 = __shfl(wl,   j + 3, 64);
      float h0 = h[(size_t)s0 * HID + lane];
      float h1 = h[(size_t)s1 * HID + lane];
      float h2 = h[(size_t)s2 * HID + lane];
      float h3 = h[(size_t)s3 * HID + lane];
      acc = fmaf(w0, h0, acc);
      acc = fmaf(w1, h1, acc);
      acc = fmaf(w2, h2, acc);
      acc = fmaf(w3, h3, acc);
    }
    for (; j < cnt; ++j) {
      int   sj = __shfl(srcl, j, 64);
      float wj = __shfl(wl,   j, 64);
      acc = fmaf(wj, h[(size_t)sj * HID + lane], acc);
    }
  }

  float v = fmaxf(acc + bias[lane], 0.f);
  float z = v * W_lin[lane];
#pragma unroll
  for (int o = 32; o; o >>= 1) z += __shfl_xor(z, o, 64);
  if (lane == 0) {
    z += b_lin[0];
    y[node] = 1.f / (1.f + expf(-z));
  }
}

// ---------------------------------------------------------------------------

extern "C" void kernel_launch(void* const* d_in, const int* in_sizes, int n_in,
                              void* d_out, int out_size, void* d_ws, size_t ws_size,
                              hipStream_t stream)
{
  const float* x     = (const float*)d_in[0];
  const int*   ei    = (const int*)d_in[1];
  const float* W     = (const float*)d_in[2];
  const float* att_s = (const float*)d_in[3];
  const float* att_d = (const float*)d_in[4];
  const float* bias  = (const float*)d_in[5];
  const float* W_lin = (const float*)d_in[6];
  const float* b_lin = (const float*)d_in[7];
  float* y = (float*)d_out;

  const int n = in_sizes[0] / IND;
  const int E = in_sizes[1] / 2;
  const long long E2 = (long long)E + n;
  const int nblk  = (int)((E2 + EPB - 1) / EPB);         // sort blocks (208)
  const int nbuck = (n + (1 << CBSHIFT) - 1) >> CBSHIFT; // coarse buckets (196)
  const int cntN  = nbuck * nblk;                        // cnt matrix (40768)
  const int nbs   = (cntN + 255) / 256;                  // scan blocks (160)

  // Workspace carve-up (~24 MB). No memsets needed: every buffer is fully
  // written before being read, every call.
  char* ws = (char*)d_ws;
  float*    h      = (float*)ws;    ws += (size_t)n * HID * sizeof(float);
  float*    a_src  = (float*)ws;    ws += (size_t)n * sizeof(float);
  float*    a_dst  = (float*)ws;    ws += (size_t)n * sizeof(float);
  int*      row_st = (int*)ws;      ws += (size_t)(n + 1) * sizeof(int);
  int*      cnt    = (int*)ws;      ws += (size_t)cntN * sizeof(int);
  int*      cntS   = (int*)ws;      ws += (size_t)cntN * sizeof(int);
  int*      bsums  = (int*)ws;      ws += (size_t)1024 * sizeof(int);
  unsigned* tmp    = (unsigned*)ws; ws += (size_t)E2 * sizeof(unsigned);
  float2*   csr    = (float2*)ws;   ws += (size_t)E2 * sizeof(float2);

  k_cnt<<<nblk, 256, 0, stream>>>(ei, cnt, E, E2, nblk, nbuck);
  k_scan_a<<<nbs, 256, 0, stream>>>(cnt, bsums, cntN);
  k_scan_b<<<1, 1024, 0, stream>>>(bsums, nbs);
  k_scan_c<<<nbs, 256, 0, stream>>>(cnt, bsums, cntS, cntN);

  k_proj<<<(n + 63) / 64, 256, 0, stream>>>(x, W, att_s, att_d, h, a_src, a_dst, n);

  k_sortout<<<nblk, 256, 0, stream>>>(ei, cntS, tmp, E, E2, nblk, nbuck);
  k_csr<<<nbuck, 256, 0, stream>>>(tmp, cntS, a_src, a_dst, row_st, csr,
                                   (int)E2, n, nblk, nbuck);

  k_gather_final<<<(n + 3) / 4, 256, 0, stream>>>(
      row_st, csr, h, bias, W_lin, b_lin, y, n);
}